// Round 1
// 199.428 us; speedup vs baseline: 1.0300x; 1.0300x over previous
//
#include <hip/hip_runtime.h>
#include <hip/hip_bf16.h>

#define N_NODES 50000
#define N_EDGES 800000
#define HEADS   4
#define NEG_SLOPE 0.2f
#define SB      256
#define NB      ((N_NODES + SB - 1) / SB)   // 196 blocks for cnt-zeroing
#define NTILE   17                    // 16 xt tiles + 1 attention tile
#define CAP     64                    // bucket capacity; P(deg>64)~1e-18/node
#define NT      ((N_NODES + 63) / 64)       // 782 mid blocks
#define EPB     1024                  // edges scattered per mid block
#define INV_LN2 1.44269504088896340736f

typedef __attribute__((ext_vector_type(8))) _Float16 half8;  // 8 f16 (4 VGPRs)
typedef __attribute__((ext_vector_type(4))) float f32x4;     // MFMA acc
typedef __attribute__((ext_vector_type(8))) unsigned short u16x8; // 16B of f16 bits

template <typename T> __device__ __forceinline__ float cvt(T v);
template <> __device__ __forceinline__ float cvt<float>(float v) { return v; }
template <> __device__ __forceinline__ float cvt<__hip_bfloat16>(__hip_bfloat16 v) {
    return __bfloat162float(v);
}
__device__ __forceinline__ unsigned short f2h(float f) {     // f32 -> f16 bits (RNE)
    _Float16 h = (_Float16)f;
    return __builtin_bit_cast(unsigned short, h);
}
__device__ __forceinline__ float hbits(unsigned short u) {   // f16 bits -> f32
    return (float)__builtin_bit_cast(_Float16, u);           // folds into v_fma_mix
}
__device__ __forceinline__ int probe_fp32(const unsigned* xw) {
    int sane = 0;
    for (int j = 0; j < 64; ++j) {
        unsigned e = (xw[j] >> 7) & 0xFF;    // exponent of low half viewed as bf16
        sane += (e >= 90 && e <= 141);
    }
    return sane < 32;                        // junk low halves => fp32 buffer
}
__device__ __forceinline__ float loadW(int isf32, const void* W, int idx) {
    return isf32 ? ((const float*)W)[idx]
                 : cvt<__hip_bfloat16>(((const __hip_bfloat16*)W)[idx]);
}

// load 8 contiguous elems as f16, vectorized (b128 loads)
template <typename T>
__device__ __forceinline__ void load8_f16(const T* p, _Float16* dst);
template <>
__device__ __forceinline__ void load8_f16<float>(const float* p, _Float16* dst) {
    float4 a = *(const float4*)p;            // 32B-aligned (offsets are 8-float mult.)
    float4 b = *(const float4*)(p + 4);
    dst[0] = (_Float16)a.x; dst[1] = (_Float16)a.y;
    dst[2] = (_Float16)a.z; dst[3] = (_Float16)a.w;
    dst[4] = (_Float16)b.x; dst[5] = (_Float16)b.y;
    dst[6] = (_Float16)b.z; dst[7] = (_Float16)b.w;
}
template <>
__device__ __forceinline__ void load8_f16<__hip_bfloat16>(const __hip_bfloat16* p,
                                                          _Float16* dst) {
    uint4 a = *(const uint4*)p;              // 8 bf16 = 16B
    const unsigned short* u = (const unsigned short*)&a;
#pragma unroll
    for (int j = 0; j < 8; ++j)
        dst[j] = (_Float16)__uint_as_float(((unsigned)u[j]) << 16);
}

// bias/fc_w pair load: elements 2i, 2i+1 as f32
template <typename T> __device__ __forceinline__ float2 load2(const T* p, int i);
template <> __device__ __forceinline__ float2 load2<float>(const float* p, int i) {
    return ((const float2*)p)[i];
}
template <> __device__ __forceinline__ float2 load2<__hip_bfloat16>(
        const __hip_bfloat16* p, int i) {
    unsigned u = ((const unsigned*)p)[i];
    return make_float2(__uint_as_float(u << 16), __uint_as_float(u & 0xffff0000u));
}

// ------------- fused init: zero cnt + probes + PARALLEL B-tile pack ----------
// flags[0]: edge_index is int64. flags[1]: float inputs are fp32.
// Blocks 0..NB-1: zero cnt (+ block 0 publishes probes).
// Blocks NB+tt (tt=0..16): pack B-tile tt. Tile 16 = att-fold WaS/WaD scaled
// by 1/ln2 (leaky commutes with positive scale => exp2(scaled) == exp(raw)).
// B layout (HW-verified R9-R15): value(l,q,j) = B[k=q*32+(l>>4)*8+j][n=l&15].
__global__ __launch_bounds__(256) void k_init(const unsigned* __restrict__ xw,
                                              const int* __restrict__ ei,
                                              const void* __restrict__ W,
                                              const void* __restrict__ att_src,
                                              const void* __restrict__ att_dst,
                                              int* __restrict__ cnt,
                                              int* __restrict__ flags,
                                              unsigned short* __restrict__ Bpack) {
    __shared__ float waS[256], waD[256];
    __shared__ int f32sh;
    if (blockIdx.x < NB) {
        int i = blockIdx.x * blockDim.x + threadIdx.x;
        if (i < N_NODES) cnt[i] = 0;
        if (blockIdx.x == 0 && threadIdx.x == 0) {
            int all0 = 1;
            for (int j = 1; j < 64; j += 2) all0 &= (ei[j] == 0);
            flags[0] = all0;
            flags[1] = probe_fp32(xw);
        }
        return;
    }
    const int tt = blockIdx.x - NB;          // 0..16
    if (threadIdx.x == 0) f32sh = probe_fp32(xw);   // local probe (race-free)
    __syncthreads();
    const int isf32 = f32sh;
    if (tt == 16) {
        int t = threadIdx.x, k = t >> 2, h = t & 3;
        float s = 0.f, d = 0.f;
        for (int c = 0; c < 64; ++c) {
            float w = loadW(isf32, W, k * 256 + h * 64 + c);
            float as = isf32 ? ((const float*)att_src)[h * 64 + c]
                             : cvt<__hip_bfloat16>(((const __hip_bfloat16*)att_src)[h * 64 + c]);
            float ad = isf32 ? ((const float*)att_dst)[h * 64 + c]
                             : cvt<__hip_bfloat16>(((const __hip_bfloat16*)att_dst)[h * 64 + c]);
            s = fmaf(w, as, s);
            d = fmaf(w, ad, d);
        }
        waS[t] = s * INV_LN2;
        waD[t] = d * INV_LN2;
        __syncthreads();
        if (threadIdx.x < 128) {
            int r = threadIdx.x;
            int q = (r >> 6) & 1, l = r & 63, n = l & 15;
            int kbase = q * 32 + ((l >> 4) & 3) * 8;
#pragma unroll
            for (int j = 0; j < 8; ++j) {
                int kk = kbase + j;
                float v = (n < 4) ? waS[kk * 4 + n]
                        : (n < 8) ? waD[kk * 4 + (n - 4)] : 0.f;
                Bpack[(16 * 128 + r) * 8 + j] = f2h(v);
            }
        }
    } else {
        if (threadIdx.x < 128) {
            int r = threadIdx.x;
            int q = (r >> 6) & 1, l = r & 63, n = l & 15;
            int kbase = q * 32 + ((l >> 4) & 3) * 8;
            int col = tt * 16 + n;
            int oc = (col & 3) * 64 + (col >> 2);   // column-permuted W
#pragma unroll
            for (int j = 0; j < 8; ++j)
                Bpack[(tt * 128 + r) * 8 + j] = f2h(loadW(isf32, W, (kbase + j) * 256 + oc));
        }
    }
}

// ---------------- MFMA transform body: xt = x @ Wp + attention logits --------
// Block = 64 rows, 4 waves; wave w: rows 16w..16w+15, 17 n-tiles, K=64.
// C layout (HW-verified): col=lane&15, row=quad*4+reg. Tile 16 cols 0..7 are
// (1/ln2-scaled) a_src/a_dst heads -> direct fp32 global writes. xt as f16.
template <typename T>
__device__ __forceinline__ void gemm_body(const T* __restrict__ x,
                                          const unsigned short* __restrict__ Bpack,
                                          unsigned short* __restrict__ xt,
                                          float* __restrict__ a_src,
                                          float* __restrict__ a_dst,
                                          unsigned short* __restrict__ tile) {
    const int tid = threadIdx.x;
    const int wav = tid >> 6, lane = tid & 63;
    const int quad = lane >> 4, r15 = lane & 15;
    const int m0 = blockIdx.x * 64;
    int gr = m0 + wav * 16 + r15;               // this lane's A row (m = lane&15)
    if (gr >= N_NODES) gr = N_NODES - 1;        // clamp; stores guarded
    half8 afrag[2];
#pragma unroll
    for (int q = 0; q < 2; ++q) {
        _Float16 tmp[8];
        load8_f16<T>(x + (size_t)gr * 64 + q * 32 + quad * 8, tmp);
#pragma unroll
        for (int j = 0; j < 8; ++j) afrag[q][j] = tmp[j];
    }
    f32x4 acc[NTILE];
#pragma unroll
    for (int t = 0; t < NTILE; ++t) acc[t] = (f32x4){0.f, 0.f, 0.f, 0.f};
    const half8* bp = (const half8*)Bpack;
#pragma unroll
    for (int t = 0; t < NTILE; ++t) {
        half8 b0 = bp[(t * 2 + 0) * 64 + lane];   // L1-resident (34 KB total)
        half8 b1 = bp[(t * 2 + 1) * 64 + lane];
        acc[t] = __builtin_amdgcn_mfma_f32_16x16x32_f16(afrag[0], b0, acc[t], 0, 0, 0);
        acc[t] = __builtin_amdgcn_mfma_f32_16x16x32_f16(afrag[1], b1, acc[t], 0, 0, 0);
    }
#pragma unroll
    for (int t = 0; t < 16; ++t)
#pragma unroll
        for (int r = 0; r < 4; ++r)
            tile[(wav * 16 + quad * 4 + r) * 264 + t * 16 + r15] = f2h(acc[t][r]);
    if (r15 < 8) {                               // tile 16: scaled logits, fp32
#pragma unroll
        for (int r = 0; r < 4; ++r) {
            int grow = m0 + wav * 16 + quad * 4 + r;
            if (grow < N_NODES) {
                if (r15 < 4) a_src[grow * HEADS + r15]       = acc[16][r];
                else         a_dst[grow * HEADS + (r15 - 4)] = acc[16][r];
            }
        }
    }
    __syncthreads();
    for (int idx = tid; idx < 64 * 32; idx += 256) {   // 64 rows x 32 chunks x 16B
        int row = idx >> 5, cc = idx & 31;
        int grow = m0 + row;
        if (grow < N_NODES) {
            uint4 v = *(const uint4*)&tile[row * 264 + cc * 8];
            *(uint4*)(xt + (size_t)grow * 256 + cc * 8) = v;
        }
    }
}

// ---------------- fused mid: every block scatters EPB edges AND transforms ---
// Atomics ISSUED before the GEMM, results USED after — vmcnt wait hides
// behind the MFMA phase. col_pad is uint16 (src < 65536) to halve the
// write-allocate amplification of the random scatter stores.
__global__ __launch_bounds__(256) void k_mid(const void* __restrict__ x,
                                             const unsigned short* __restrict__ Bpack,
                                             const int* __restrict__ ei,
                                             const int* __restrict__ flags,
                                             int* __restrict__ cnt,
                                             unsigned short* __restrict__ col_pad,
                                             unsigned short* __restrict__ xt,
                                             float* __restrict__ a_src,
                                             float* __restrict__ a_dst) {
    __shared__ unsigned short tile[64 * 264];   // ONE 33.8 KB allocation
    const int f64 = flags[0];
    const int base = blockIdx.x * EPB + threadIdx.x;
    int srcv[4], dstv[4], pos[4];
#pragma unroll
    for (int k = 0; k < 4; ++k) {
        int t = base + k * 256;
        if (t < N_EDGES) {
            if (f64) { srcv[k] = ei[2 * t]; dstv[k] = ei[2 * N_EDGES + 2 * t]; }
            else     { srcv[k] = ei[t];     dstv[k] = ei[N_EDGES + t]; }
        } else dstv[k] = -1;
    }
#pragma unroll
    for (int k = 0; k < 4; ++k)
        if (dstv[k] >= 0) pos[k] = atomicAdd(cnt + dstv[k], 1);
    // ---- transform my 64 rows (atomic returns not yet consumed) ----
    if (flags[1]) gemm_body<float>((const float*)x, Bpack, xt, a_src, a_dst, tile);
    else          gemm_body<__hip_bfloat16>((const __hip_bfloat16*)x, Bpack, xt,
                                            a_src, a_dst, tile);
    // ---- deferred scatter stores ----
#pragma unroll
    for (int k = 0; k < 4; ++k)
        if (dstv[k] >= 0 && pos[k] < CAP)
            col_pad[dstv[k] * CAP + pos[k]] = (unsigned short)srcv[k];
}

// 8 fma_mix per gathered row-half: x = 16B of f16 (cols 8*l5..8*l5+7),
// p = this row's pe; col c -> head c&3, channel c>>2.
__device__ __forceinline__ void acc8(u16x8 x, float4 p, float v[8]) {
    v[0] = fmaf(p.x, hbits(x[0]), v[0]); v[1] = fmaf(p.y, hbits(x[1]), v[1]);
    v[2] = fmaf(p.z, hbits(x[2]), v[2]); v[3] = fmaf(p.w, hbits(x[3]), v[3]);
    v[4] = fmaf(p.x, hbits(x[4]), v[4]); v[5] = fmaf(p.y, hbits(x[5]), v[5]);
    v[6] = fmaf(p.z, hbits(x[6]), v[6]); v[7] = fmaf(p.w, hbits(x[7]), v[7]);
}

// ---------------- fused aggregate: softmax + weighted sum + mean/bias/relu/fc
// One wave per dst node. Edge list = lanes 0..n-1, SELF LOOP folded in as
// lane n (same gather path, pad lanes carry pe=0 and point at the self row
// so the even-pad read is L2-hot). Denominators: ONE shfl_xor tree per wave
// (pe kept in registers) instead of 4 redundant adds/edge in the hot loop.
// xt gather: TWO rows per global_load_dwordx4 — lanes 0..31 read row j
// (16 B each), lanes 32..63 read row j+1; each lane accumulates 8 values
// (2 channels x 4 heads); one shfl_xor(32) fold combines the halves.
template <typename T>
__device__ __forceinline__ void agg_body(const int* __restrict__ cnt,
                                         const unsigned short* __restrict__ col_pad,
                                         const float* __restrict__ a_src,
                                         const float* __restrict__ a_dst,
                                         const unsigned short* __restrict__ xt,
                                         const T* __restrict__ bias,
                                         const T* __restrict__ fc_w,
                                         const T* __restrict__ fc_b,
                                         float* __restrict__ out,
                                         int* __restrict__ cS,
                                         float4* __restrict__ peS) {
    const int tid = threadIdx.x;
    const int wav = tid >> 6, lane = tid & 63;
    const int hlf = lane >> 5, l5 = lane & 31;
    const int wid = (blockIdx.x * blockDim.x + tid) >> 6;   // dst node
    if (wid >= N_NODES) return;
    int* cSw = cS + wav * 64;
    float4* peSw = peS + wav * 64;
    int n = cnt[wid]; n = n > (CAP - 1) ? (CAP - 1) : n;    // keep slot for self
    const float4 ad = ((const float4*)a_dst)[wid];          // uniform
    // ---- per-lane edge setup: lanes 0..n-1 edges, lane n = self loop -------
    int mycol = wid;
    if (lane < n) mycol = (int)col_pad[wid * CAP + lane];   // coalesced u16
    const float4 as = ((const float4*)a_src)[mycol];
    float e0 = as.x + ad.x, e1 = as.y + ad.y;
    float e2 = as.z + ad.z, e3 = as.w + ad.w;
    e0 = e0 > 0.f ? e0 : NEG_SLOPE * e0;  e1 = e1 > 0.f ? e1 : NEG_SLOPE * e1;
    e2 = e2 > 0.f ? e2 : NEG_SLOPE * e2;  e3 = e3 > 0.f ? e3 : NEG_SLOPE * e3;
    float4 pe = make_float4(exp2f(e0), exp2f(e1), exp2f(e2), exp2f(e3));
    if (lane > n) pe = make_float4(0.f, 0.f, 0.f, 0.f);     // pad lanes
    cSw[lane] = mycol << 9;                                 // xt row BYTE offset
    peSw[lane] = pe;                                        // wave-sync LDS (in-order DS)
    // ---- gather & accumulate: 2 rows / dwordx4 ----------------------------
    const char* xtb = (const char*)xt + l5 * 16;            // my 16B slice
    float v[8] = {0.f, 0.f, 0.f, 0.f, 0.f, 0.f, 0.f, 0.f};
    const int m2 = (n + 2) & ~1;                            // n+1 entries, even-pad
    int j = 0;
    for (; j + 8 <= m2; j += 8) {
        int c0 = cSw[j + hlf],     c1 = cSw[j + 2 + hlf];
        int c2 = cSw[j + 4 + hlf], c3 = cSw[j + 6 + hlf];
        u16x8 xA = *(const u16x8*)(xtb + c0);
        u16x8 xB = *(const u16x8*)(xtb + c1);
        u16x8 xC = *(const u16x8*)(xtb + c2);
        u16x8 xD = *(const u16x8*)(xtb + c3);
        float4 pA = peSw[j + hlf],     pB = peSw[j + 2 + hlf];
        float4 pC = peSw[j + 4 + hlf], pD = peSw[j + 6 + hlf];
        acc8(xA, pA, v); acc8(xB, pB, v); acc8(xC, pC, v); acc8(xD, pD, v);
    }
    for (; j < m2; j += 2) {
        int c0 = cSw[j + hlf];
        u16x8 xA = *(const u16x8*)(xtb + c0);
        float4 pA = peSw[j + hlf];
        acc8(xA, pA, v);
    }
    // ---- denominators: one tree for the whole wave (pe=0 on pad lanes) ----
    float sp0 = pe.x, sp1 = pe.y, sp2 = pe.z, sp3 = pe.w;
#pragma unroll
    for (int off = 32; off > 0; off >>= 1) {
        sp0 += __shfl_xor(sp0, off, 64);
        sp1 += __shfl_xor(sp1, off, 64);
        sp2 += __shfl_xor(sp2, off, 64);
        sp3 += __shfl_xor(sp3, off, 64);
    }
    // ---- fold the two 32-lane halves (same channels, disjoint edges) ------
#pragma unroll
    for (int k = 0; k < 8; ++k) v[k] += __shfl_xor(v[k], 32, 64);
    const float r0 = 0.25f / sp0, r1 = 0.25f / sp1;
    const float r2 = 0.25f / sp2, r3 = 0.25f / sp3;
    const float2 bi = load2<T>(bias, l5);
    const float2 fw = load2<T>(fc_w, l5);
    float oc0 = fmaf(v[0], r0, fmaf(v[1], r1, fmaf(v[2], r2, v[3] * r3))) + bi.x;
    float oc1 = fmaf(v[4], r0, fmaf(v[5], r1, fmaf(v[6], r2, v[7] * r3))) + bi.y;
    oc0 = oc0 > 0.f ? oc0 : 0.f;                 // relu
    oc1 = oc1 > 0.f ? oc1 : 0.f;
    float o = oc0 * fw.x + oc1 * fw.y;           // fc over my 2 channels
#pragma unroll
    for (int off = 16; off > 0; off >>= 1) o += __shfl_down(o, off, 64);
    if (lane == 0) out[wid] = o + cvt<T>(fc_b[0]);   // lane0 = sum of lanes 0..31
}

__global__ __launch_bounds__(256) void k_aggregate(const int* __restrict__ cnt,
                                                   const unsigned short* __restrict__ col_pad,
                                                   const float* __restrict__ a_src,
                                                   const float* __restrict__ a_dst,
                                                   const unsigned short* __restrict__ xt,
                                                   const void* __restrict__ bias,
                                                   const void* __restrict__ fc_w,
                                                   const void* __restrict__ fc_b,
                                                   const int* __restrict__ flags,
                                                   float* __restrict__ out) {
    __shared__ int4   cS4[4 * 16];              // 16B-aligned
    __shared__ float4 peS[4 * 64];
    int* cS = (int*)cS4;
    if (flags[1])
        agg_body<float>(cnt, col_pad, a_src, a_dst, xt, (const float*)bias,
                        (const float*)fc_w, (const float*)fc_b, out, cS, peS);
    else
        agg_body<__hip_bfloat16>(cnt, col_pad, a_src, a_dst, xt,
                                 (const __hip_bfloat16*)bias,
                                 (const __hip_bfloat16*)fc_w,
                                 (const __hip_bfloat16*)fc_b, out, cS, peS);
}

extern "C" void kernel_launch(void* const* d_in, const int* in_sizes, int n_in,
                              void* d_out, int out_size, void* d_ws, size_t ws_size,
                              hipStream_t stream) {
    const void* x       = d_in[0];
    const int*  ei      = (const int*)d_in[1];
    const void* W       = d_in[2];
    const void* att_src = d_in[3];
    const void* att_dst = d_in[4];
    const void* bias    = d_in[5];
    const void* fc_w    = d_in[6];
    const void* fc_b    = d_in[7];
    float* out = (float*)d_out;

    char* wsb = (char*)d_ws;
    unsigned short* xt = (unsigned short*)wsb;                   // 25.6 MB (f16)
    unsigned short* Bpack = (unsigned short*)(wsb + (size_t)N_NODES * 512); // 34 KB
    float*  a_src  = (float*)(Bpack + NTILE * 1024);             // 800 KB (16B aligned)
    float*  a_dst  = a_src + N_NODES * HEADS;                    // 800 KB (16B aligned)
    unsigned short* col_pad = (unsigned short*)(a_dst + N_NODES * HEADS);  // 6.4 MB
    int*    cnt    = (int*)(col_pad + (size_t)N_NODES * CAP);    // 200 KB
    int*    flags  = cnt + N_NODES;

    k_init<<<NB + NTILE, 256, 0, stream>>>((const unsigned*)x, ei, W, att_src,
                                           att_dst, cnt, flags, Bpack);
    k_mid<<<NT, 256, 0, stream>>>(x, Bpack, ei, flags, cnt, col_pad,
                                  xt, a_src, a_dst);
    k_aggregate<<<((size_t)N_NODES * 64 + 255) / 256, 256, 0, stream>>>(
        cnt, col_pad, a_src, a_dst, xt, bias, fc_w, fc_b, flags, out);
}